// Round 11
// baseline (920.899 us; speedup 1.0000x reference)
//
#include <hip/hip_runtime.h>

// RSSM v11 = v5 (verified best: seq 522us) + P1 job1 GRU weights parked in
// AGPRs. The VGPR allocator clamps this kernel to 128 regs (r2/r6/r8), but
// AGPRs are a separate class: park 27 units (108 regs) once via
// v_accvgpr_write ("a"-constraint vars), fetch in-loop via v_accvgpr_read
// (~2cy vs ~200cy L2). 128 VGPR + 108 AGPR = 236 <= 256 unified @ 2 waves/EU.
// P1 L2 stream per wave: 54->27 loads (waves 3-7), 27->0 (waves 0-2).
// Everything else byte-identical to v5.

typedef unsigned short u16;
typedef unsigned int u32;
typedef __attribute__((ext_vector_type(8))) short short8;
typedef __attribute__((ext_vector_type(4))) float f32x4;
typedef __attribute__((ext_vector_type(4))) int i32x4;

#define LL 64
#define OBS_ 200
#define ACT_ 6
#define STO 30
#define OUTC 350

// packed-weight unit offsets (1 unit = 1KB = 64 lanes x 16B)
#define U_WG   0
#define U_PW1  468
#define U_QW1  559
#define U_PW2  741
#define U_QW2  769
#define U_TOT  797
#define QX_OFF (1u << 20)

__device__ __forceinline__ u16 f2b(float f){
  u32 u = __float_as_uint(f);
  u = (u + 0x7fffu + ((u >> 16) & 1u)) >> 16;   // RNE
  return (u16)u;
}
__device__ __forceinline__ float b2f(u16 h){ return __uint_as_float(((u32)h) << 16); }

// ---- AGPR park/fetch (allocator-assigned "a"-class, no physical clashes) ----
__device__ __forceinline__ void park(int (&d)[4], short8 v){
  i32x4 s = *(i32x4*)&v;
  asm("v_accvgpr_write_b32 %0, %1" : "=a"(d[0]) : "v"(s[0]));
  asm("v_accvgpr_write_b32 %0, %1" : "=a"(d[1]) : "v"(s[1]));
  asm("v_accvgpr_write_b32 %0, %1" : "=a"(d[2]) : "v"(s[2]));
  asm("v_accvgpr_write_b32 %0, %1" : "=a"(d[3]) : "v"(s[3]));
}
__device__ __forceinline__ short8 fet(const int (&s)[4]){
  int t0, t1, t2, t3;
  asm("v_accvgpr_read_b32 %0, %1" : "=v"(t0) : "a"(s[0]));
  asm("v_accvgpr_read_b32 %0, %1" : "=v"(t1) : "a"(s[1]));
  asm("v_accvgpr_read_b32 %0, %1" : "=v"(t2) : "a"(s[2]));
  asm("v_accvgpr_read_b32 %0, %1" : "=v"(t3) : "a"(s[3]));
  i32x4 r{t0, t1, t2, t3};
  return *(short8*)&r;
}

// stride-512B tiles (h): swizzle byte ^= (r&7)<<4
__device__ __forceinline__ short8 ldA7(const u16* buf, int r, int colStart){
  return *(const short8*)((const char*)buf + r*512 + ((colStart*2) ^ ((r & 7) << 4)));
}
__device__ __forceinline__ void st27(u16* buf, int r, int c, u16 v){
  *(u16*)((char*)buf + r*512 + ((c*2) ^ ((r & 7) << 4))) = v;
}
__device__ __forceinline__ u16 ld27(const u16* buf, int r, int c){
  return *(const u16*)((const char*)buf + r*512 + ((c*2) ^ ((r & 7) << 4)));
}
// stride-448B tiles (sqq/sob/shh/spp): swizzle byte ^= (r&3)<<4
__device__ __forceinline__ short8 ldA3(const u16* buf, int r, int colStart){
  return *(const short8*)((const char*)buf + r*448 + ((colStart*2) ^ ((r & 3) << 4)));
}
__device__ __forceinline__ void st23(u16* buf, int r, int c, u16 v){
  *(u16*)((char*)buf + r*448 + ((c*2) ^ ((r & 3) << 4))) = v;
}
__device__ __forceinline__ void st8_3(u16* buf, int r, int c8, short8 v){
  *(short8*)((char*)buf + r*448 + ((c8*16) ^ ((r & 3) << 4))) = v;
}
__device__ __forceinline__ short8 ldB(const char* wsb, int unit, int lane){
  return *(const short8*)(wsb + (((size_t)unit) << 10) + ((size_t)lane << 4));
}
__device__ __forceinline__ short8 lwq(const u16* sw, int lu, int lane){
  return *(const short8*)((const char*)sw + ((size_t)lu << 10) + (lane << 4));
}
__device__ __forceinline__ f32x4 mfma(short8 a, short8 b, f32x4 c){
  return __builtin_amdgcn_mfma_f32_16x16x32_bf16(a, b, c, 0, 0, 0);
}
__device__ __forceinline__ float sigm(float x){ return 1.f / (1.f + __expf(-x)); }
__device__ __forceinline__ float tanhf_(float x){
  x = fminf(fmaxf(x, -15.f), 15.f);
  float e = __expf(-2.f * x);
  return (1.f - e) / (1.f + e);
}
__device__ __forceinline__ float softplus_(float x){
  return (x > 20.f) ? x : log1pf(__expf(x));
}
__device__ __forceinline__ short8 pack8(f32x4 a, f32x4 b){
  short8 v;
  v[0]=(short)f2b(a[0]); v[1]=(short)f2b(a[1]); v[2]=(short)f2b(a[2]); v[3]=(short)f2b(a[3]);
  v[4]=(short)f2b(b[0]); v[5]=(short)f2b(b[1]); v[6]=(short)f2b(b[2]); v[7]=(short)f2b(b[3]);
  return v;
}

// ---------------- weight packing (UNCHANGED, verified round 1) ---------------
__global__ __launch_bounds__(512) void pack_w(
    const float* W_ih, const float* W_hh, const float* pW1f, const float* qW1f,
    const float* pW2f, const float* qW2f, u16* wsu)
{
  int u = blockIdx.x;
  int t = threadIdx.x;
  int lane = t >> 3, j = t & 7;
  int nl = lane & 15, kg = lane >> 4;
  float v = 0.f;
  if (u < U_PW1) {                       // WG
    int nt = u / 9, ks = u % 9;
    int k = ks*32 + kg*8 + j;
    int c = nt*16 + nl;
    int grow, part, coff;
    if (c < 208)      { grow = c;            part = 0; coff = c; }
    else if (c < 416) { grow = 200 + (c-208); part = 0; coff = c-208; }
    else if (c < 624) { grow = 400 + (c-416); part = 1; coff = c-416; }
    else              { grow = 400 + (c-624); part = 2; coff = c-624; }
    if (coff < 200) {
      if (k < 36)                  { if (part != 2) v = W_ih[grow*36 + k]; }
      else if (k >= 64 && k < 264) { if (part != 1) v = W_hh[grow*200 + (k-64)]; }
    }
  } else if (u < U_QW1) {                // PW1
    int uu = u - U_PW1; int nt = uu / 7, ks = uu % 7;
    int k = ks*32 + kg*8 + j; int n = nt*16 + nl;
    if (n < 200 && k < 200) v = pW1f[n*200 + k];
  } else if (u < U_PW2) {                // QW1
    int uu = u - U_QW1; int nt = uu / 14, ks = uu % 14;
    int k = ks*32 + kg*8 + j; int n = nt*16 + nl;
    if (n < 200) {
      if (k < 200) v = qW1f[n*400 + k];
      else if (k >= 224 && k < 424) v = qW1f[n*400 + 200 + (k-224)];
    }
  } else {                               // PW2 / QW2
    bool isQ = (u >= U_QW2);
    int uu = u - (isQ ? U_QW2 : U_PW2); int nt = uu / 7, ks = uu % 7;
    int k = ks*32 + kg*8 + j; int c = nt*16 + nl;
    int row = (c < 32) ? c : 30 + (c - 32);
    bool ok = (c < 32) ? (c < 30) : ((c - 32) < 30);
    const float* W = isQ ? qW2f : pW2f;
    if (ok && k < 200) v = W[row*200 + k];
  }
  wsu[((size_t)u << 9) + lane*8 + j] = f2b(v);
}

// ---------------- qx kernel (UNCHANGED, verified round 4) --------------------
__global__ __launch_bounds__(512) void qx_k(
    const float* __restrict__ obs, const float* __restrict__ qb1,
    const char* __restrict__ wsb, u16* __restrict__ qxp)
{
  const int tid = threadIdx.x, w = tid >> 6, lane = tid & 63;
  const int nl = lane & 15, kg = lane >> 4;
  const int r0 = blockIdx.x * 16;
  __shared__ __align__(16) u16 sob[16*224];
  for (int i = tid; i < 16*224; i += 512) sob[i] = 0;
  __syncthreads();
  if (tid < 400) {
    int m = tid / 25, c8 = tid % 25;
    const float* op = obs + (size_t)(r0+m)*OBS_ + c8*8;
    f32x4 a = *(const f32x4*)op, b = *(const f32x4*)(op + 4);
    st8_3(sob, m, c8, pack8(a, b));
  }
  __syncthreads();
#pragma unroll
  for (int qi = 0; qi < 2; ++qi) {
    int tq = w + qi*8;
    if (tq < 13) {
      f32x4 acc{0,0,0,0};
#pragma unroll
      for (int ks = 0; ks < 7; ++ks)
        acc = mfma(ldA3(sob, nl, ks*32 + kg*8), ldB(wsb, U_QW1 + tq*14 + ks, lane), acc);
      int n = tq*16 + nl;
      if (n < 200) {
        float b = qb1[n];
#pragma unroll
        for (int i = 0; i < 4; ++i)
          qxp[(size_t)(r0 + kg*4 + i)*OBS_ + n] = f2b(acc[i] + b);
      }
    }
  }
}

// ---------------- prior kernel (UNCHANGED, verified round 4) -----------------
__global__ __launch_bounds__(512) void prior_k(
    const float* __restrict__ pb1, const float* __restrict__ pb2,
    const char* __restrict__ wsb, float* __restrict__ out)
{
  const int tid = threadIdx.x, w = tid >> 6, lane = tid & 63;
  const int nl = lane & 15, kg = lane >> 4;
  const int r0 = blockIdx.x * 16;
  __shared__ __align__(16) u16 shh[16*224];
  __shared__ __align__(16) u16 spp[16*224];
  for (int i = tid; i < 16*224; i += 512) { shh[i] = 0; spp[i] = 0; }
  __syncthreads();
  if (tid < 400) {
    int m = tid / 25, c8 = tid % 25;
    const float* hp = out + (size_t)(r0+m)*OUTC + 150 + c8*8;
    f32x4 a, b;
#pragma unroll
    for (int i = 0; i < 4; ++i) { a[i] = hp[i]; b[i] = hp[4+i]; }
    st8_3(shh, m, c8, pack8(a, b));
  }
  __syncthreads();
#pragma unroll
  for (int qi = 0; qi < 2; ++qi) {
    int tq = w + qi*8;
    if (tq < 13) {
      f32x4 acc{0,0,0,0};
#pragma unroll
      for (int ks = 0; ks < 7; ++ks)
        acc = mfma(ldA3(shh, nl, ks*32 + kg*8), ldB(wsb, U_PW1 + tq*7 + ks, lane), acc);
      int n = tq*16 + nl;
      if (n < 200) {
        float b = pb1[n];
#pragma unroll
        for (int i = 0; i < 4; ++i) {
          float v = acc[i] + b;
          st23(spp, kg*4 + i, n, f2b(v > 0.f ? v : 0.f));
        }
      }
    }
  }
  __syncthreads();
  if (w < 2) {
    f32x4 a0{0,0,0,0}, a1{0,0,0,0};
#pragma unroll
    for (int ks = 0; ks < 7; ++ks) {
      short8 af = ldA3(spp, nl, ks*32 + kg*8);
      a0 = mfma(af, ldB(wsb, U_PW2 + w*7 + ks,     lane), a0);
      a1 = mfma(af, ldB(wsb, U_PW2 + (w+2)*7 + ks, lane), a1);
    }
    int c3 = w*16 + nl;
    if (c3 < 30) {
      float bmu = pb2[c3], bpre = pb2[30 + c3];
#pragma unroll
      for (int i = 0; i < 4; ++i) {
        size_t ob = (size_t)(r0 + kg*4 + i)*OUTC;
        out[ob + c3] = a0[i] + bmu;
        float sp = softplus_(a1[i] + bpre) + 1e-5f;
        out[ob + 30 + c3] = fmaxf(sp, 1e-4f);
      }
    }
  }
}

// ---------------- sequential scan v11: v5 + AGPR-parked job1 weights ---------
__global__ __launch_bounds__(512, 2) void rssm_seq(
    const float* __restrict__ act, const float* __restrict__ noise,
    const float* __restrict__ b_ih, const float* __restrict__ b_hh,
    const float* __restrict__ qb2,
    const u16* __restrict__ qxp, const char* __restrict__ wsb,
    float* __restrict__ out)
{
  const int tid  = threadIdx.x;
  const int w    = tid >> 6;      // wave 0..7
  const int lane = tid & 63;
  const int nl   = lane & 15;
  const int kg   = lane >> 4;
  const int m0   = blockIdx.x * 16;

  // LDS weight cache: 119 units = QW1h (tq*7+ks, 91) then QW2 (nt*7+ks, 28)
  __shared__ __align__(16) u16 swq[119*512];
  // h0/h1: [16][256] stride 512B: h 0..199 | s 200..229 | a 230..235 | zeros
  __shared__ __align__(16) u16 h0 [16*256];
  __shared__ __align__(16) u16 h1 [16*256];
  __shared__ __align__(16) u16 sqq[16*224];   // stride 448B

  for (int i = tid; i < 16*256; i += 512) { h0[i]=0; h1[i]=0; }
  for (int i = tid; i < 16*224; i += 512) sqq[i]=0;
  // load LDS weight cache (one-time, 119KB)
  for (int c = tid; c < 119*64; c += 512) {
    int lu = c >> 6, l16 = c & 63;
    int gu = (lu < 91) ? (U_QW1 + (lu/7)*14 + 7 + (lu%7)) : (U_QW2 + (lu - 91));
    *(short8*)((char*)swq + (size_t)c*16) =
        *(const short8*)(wsb + ((size_t)gu << 10) + (l16 << 4));
  }

  // ---- park job1 GRU weights (27 units = 108 AGPRs), loaded once ----
  int wRp[9][4], wZp[9][4], wIp[2][4], wHp[7][4];
#pragma unroll
  for (int ks = 0; ks < 9; ++ks) park(wRp[ks], ldB(wsb, U_WG + w*9 + ks, lane));
#pragma unroll
  for (int ks = 0; ks < 9; ++ks) park(wZp[ks], ldB(wsb, U_WG + (13+w)*9 + ks, lane));
  park(wIp[0], ldB(wsb, U_WG + (26+w)*9 + 0, lane));
  park(wIp[1], ldB(wsb, U_WG + (26+w)*9 + 1, lane));
#pragma unroll
  for (int ks = 0; ks < 7; ++ks) park(wHp[ks], ldB(wsb, U_WG + (39+w)*9 + 2 + ks, lane));

  // ---- roles ----
  // P1/P2 job1: tq = w (all 8 waves). job2 (waves 3..7): tq2 = w+5 (8..12).
  const int  cj  = w*16 + nl;                       // < 128, always valid
  const bool j2  = (w >= 3);
  const int  tq2 = w + 5;
  const int  cj2 = tq2*16 + nl;
  const bool cj2v = j2 && (cj2 < 200);
  const float bR1 = b_ih[cj]       + b_hh[cj];
  const float bZ1 = b_ih[200 + cj] + b_hh[200 + cj];
  const float bI1 = b_ih[400 + cj];
  const float bH1 = b_hh[400 + cj];
  float bR2=0,bZ2=0,bI2=0,bH2=0;
  if (cj2v) {
    bR2 = b_ih[cj2] + b_hh[cj2];
    bZ2 = b_ih[200+cj2] + b_hh[200+cj2];
    bI2 = b_ih[400+cj2];
    bH2 = b_hh[400+cj2];
  }
  // P3: waves 0,1 (mu tile w, pre tile w+2 of QW2)
  const bool isP3 = (w < 2);
  const int  c3   = w*16 + nl;
  const bool c3v  = isP3 && (c3 < 30);
  float b3mu=0, b3pre=0;
  if (c3v) { b3mu = qb2[c3]; b3pre = qb2[30 + c3]; }
  // act stagers: waves 2,3 (96 lanes)
  const int  t2 = (w - 2)*64 + lane;
  const bool isAct = (w == 2 || w == 3) && (t2 < 96);

  __syncthreads();
  // prologue: act(l=0) -> h0 cols 230..235 (s0=h0=0 already)
  if (tid < 96) {
    int m = tid / 6, j = tid % 6;
    st27(h0, m, 230 + j, f2b(act[(size_t)(m0+m)*LL*ACT_ + j]));
  }
  __syncthreads();

#pragma unroll 1
  for (int l = 0; l < LL; ++l) {
    u16* hO = (l & 1) ? h1 : h0;
    u16* hN = (l & 1) ? h0 : h1;
    const size_t outB = (size_t)l*OUTC;

    // ---- step-start prefetches (consumed 1-2 phases later) ----
    float ep[4] = {0,0,0,0};
    if (c3v) {
      const float* np = noise + (size_t)(m0 + kg*4)*LL*STO + (size_t)l*STO + c3;
#pragma unroll
      for (int i = 0; i < 4; ++i) ep[i] = np[(size_t)i*LL*STO];
    }
    float qx1[4], qx2[4] = {0,0,0,0};
#pragma unroll
    for (int i = 0; i < 4; ++i)
      qx1[i] = b2f(qxp[((size_t)(m0 + kg*4 + i)*LL + l)*OBS_ + cj]);
    if (cj2v) {
#pragma unroll
      for (int i = 0; i < 4; ++i)
        qx2[i] = b2f(qxp[((size_t)(m0 + kg*4 + i)*LL + l)*OBS_ + cj2]);
    }
    float av = 0.f;
    if (isAct && (l + 1 < LL))
      av = act[((size_t)(m0 + t2/6)*LL + (l+1))*ACT_ + (t2 % 6)];

    // ================= P1: GRU gates (job1 from AGPR, job2 from L2) =========
    short8 a9[9];
#pragma unroll
    for (int ks = 0; ks < 9; ++ks) {
      const int col = (ks < 2) ? (200 + ks*32 + kg*8) : ((ks-2)*32 + kg*8);
      a9[ks] = ldA7(hO, nl, col);
    }
    if (!j2) {
      f32x4 aR{0,0,0,0}, aZ{0,0,0,0}, aI{0,0,0,0}, aH{0,0,0,0};
#pragma unroll
      for (int ks = 0; ks < 9; ++ks) {
        aR = mfma(a9[ks], fet(wRp[ks]), aR);
        aZ = mfma(a9[ks], fet(wZp[ks]), aZ);
        if (ks < 2) aI = mfma(a9[ks], fet(wIp[ks]), aI);
        else        aH = mfma(a9[ks], fet(wHp[ks-2]), aH);
      }
#pragma unroll
      for (int i = 0; i < 4; ++i) {
        int m = kg*4 + i;
        float r = sigm(aR[i] + bR1);
        float z = sigm(aZ[i] + bZ1);
        float n = tanhf_(aI[i] + bI1 + r*(aH[i] + bH1));
        float hold = b2f(ld27(hO, m, cj));
        float hnew = (1.f - z)*n + z*hold;
        st27(hN, m, cj, f2b(hnew));
        out[(size_t)(m0+m)*LL*OUTC + outB + 150 + cj] = hnew;
      }
    } else {
      f32x4 aR1{0,0,0,0}, aZ1{0,0,0,0}, aI1{0,0,0,0}, aH1{0,0,0,0};
      f32x4 aR2{0,0,0,0}, aZ2{0,0,0,0}, aI2{0,0,0,0}, aH2{0,0,0,0};
#pragma unroll
      for (int ks = 0; ks < 9; ++ks) {
        aR1 = mfma(a9[ks], fet(wRp[ks]), aR1);
        aR2 = mfma(a9[ks], ldB(wsb, U_WG + tq2*9 + ks,      lane), aR2);
        aZ1 = mfma(a9[ks], fet(wZp[ks]), aZ1);
        aZ2 = mfma(a9[ks], ldB(wsb, U_WG + (13+tq2)*9 + ks, lane), aZ2);
        if (ks < 2) {
          aI1 = mfma(a9[ks], fet(wIp[ks]), aI1);
          aI2 = mfma(a9[ks], ldB(wsb, U_WG + (26+tq2)*9 + ks, lane), aI2);
        } else {
          aH1 = mfma(a9[ks], fet(wHp[ks-2]), aH1);
          aH2 = mfma(a9[ks], ldB(wsb, U_WG + (39+tq2)*9 + ks, lane), aH2);
        }
      }
#pragma unroll
      for (int i = 0; i < 4; ++i) {
        int m = kg*4 + i;
        float r = sigm(aR1[i] + bR1);
        float z = sigm(aZ1[i] + bZ1);
        float n = tanhf_(aI1[i] + bI1 + r*(aH1[i] + bH1));
        float hold = b2f(ld27(hO, m, cj));
        float hnew = (1.f - z)*n + z*hold;
        st27(hN, m, cj, f2b(hnew));
        out[(size_t)(m0+m)*LL*OUTC + outB + 150 + cj] = hnew;
      }
      if (cj2 < 200) {
#pragma unroll
        for (int i = 0; i < 4; ++i) {
          int m = kg*4 + i;
          float r = sigm(aR2[i] + bR2);
          float z = sigm(aZ2[i] + bZ2);
          float n = tanhf_(aI2[i] + bI2 + r*(aH2[i] + bH2));
          float hold = b2f(ld27(hO, m, cj2));
          float hnew = (1.f - z)*n + z*hold;
          st27(hN, m, cj2, f2b(hnew));
          out[(size_t)(m0+m)*LL*OUTC + outB + 150 + cj2] = hnew;
        }
      }
    }
    __syncthreads();

    // ================= P2: q1h GEMM (LDS weights) ===========================
    {
      short8 g[7];
#pragma unroll
      for (int ks = 0; ks < 7; ++ks) g[ks] = ldA7(hN, nl, ks*32 + kg*8);
      f32x4 aq1{0,0,0,0}, aq2{0,0,0,0};
#pragma unroll
      for (int ks = 0; ks < 7; ++ks) {
        aq1 = mfma(g[ks], lwq(swq, w*7 + ks, lane), aq1);
        if (j2) aq2 = mfma(g[ks], lwq(swq, tq2*7 + ks, lane), aq2);
      }
#pragma unroll
      for (int i = 0; i < 4; ++i) {
        int m = kg*4 + i;
        float v = aq1[i] + qx1[i];
        st23(sqq, m, cj, f2b(v > 0.f ? v : 0.f));
      }
      if (cj2v) {
#pragma unroll
        for (int i = 0; i < 4; ++i) {
          int m = kg*4 + i;
          float v = aq2[i] + qx2[i];
          st23(sqq, m, cj2, f2b(v > 0.f ? v : 0.f));
        }
      }
    }
    __syncthreads();

    // ================= P3: q2 heads + reparam (waves 0,1; LDS weights) ======
    if (isP3) {
      f32x4 a0{0,0,0,0}, a1{0,0,0,0};
#pragma unroll
      for (int ks = 0; ks < 7; ++ks) {
        short8 af = ldA3(sqq, nl, ks*32 + kg*8);
        a0 = mfma(af, lwq(swq, 91 + w*7 + ks,     lane), a0);
        a1 = mfma(af, lwq(swq, 91 + (w+2)*7 + ks, lane), a1);
      }
      if (c3 < 30) {
#pragma unroll
        for (int i = 0; i < 4; ++i) {
          int m = kg*4 + i;
          size_t ob = (size_t)(m0+m)*LL*OUTC + outB;
          float mu = a0[i] + b3mu;
          float sp = softplus_(a1[i] + b3pre) + 1e-5f;
          float sd = fmaxf(sp, 1e-4f);
          float s = mu + sd*ep[i];
          out[ob +  60 + c3] = mu;
          out[ob +  90 + c3] = sd;
          out[ob + 120 + c3] = s;
          st27(hN, m, 200 + c3, f2b(s));
        }
      }
    } else if (isAct && (l + 1 < LL)) {
      st27(hN, t2/6, 230 + (t2 % 6), f2b(av));
    }
    __syncthreads();
  }
}

extern "C" void kernel_launch(void* const* d_in, const int* in_sizes, int n_in,
                              void* d_out, int out_size, void* d_ws, size_t ws_size,
                              hipStream_t stream) {
  const float* obs   = (const float*)d_in[0];
  const float* act   = (const float*)d_in[1];
  const float* noise = (const float*)d_in[2];
  const float* W_ih  = (const float*)d_in[3];
  const float* b_ih  = (const float*)d_in[4];
  const float* W_hh  = (const float*)d_in[5];
  const float* b_hh  = (const float*)d_in[6];
  const float* pW1   = (const float*)d_in[7];
  const float* pb1   = (const float*)d_in[8];
  const float* pW2   = (const float*)d_in[9];
  const float* pb2   = (const float*)d_in[10];
  const float* qW1   = (const float*)d_in[11];
  const float* qb1   = (const float*)d_in[12];
  const float* qW2   = (const float*)d_in[13];
  const float* qb2   = (const float*)d_in[14];
  float* out = (float*)d_out;
  u16* qxp = (u16*)((char*)d_ws + QX_OFF);

  pack_w<<<U_TOT, 512, 0, stream>>>(W_ih, W_hh, pW1, qW1, pW2, qW2, (u16*)d_ws);
  qx_k<<<8192, 512, 0, stream>>>(obs, qb1, (const char*)d_ws, qxp);
  rssm_seq<<<128, 512, 0, stream>>>(act, noise, b_ih, b_hh, qb2,
                                    qxp, (const char*)d_ws, out);
  prior_k<<<8192, 512, 0, stream>>>(pb1, pb2, (const char*)d_ws, out);
}

// Round 12
// 764.470 us; speedup vs baseline: 1.2046x; 1.2046x over previous
//
#include <hip/hip_runtime.h>

// RSSM v12 = v5 verbatim (verified best: seq 522us, total 617us).
// Neighborhood search complete (r6-r11): barrier type (BAR -145us worse),
// phase split (-118us worse), 768/1024-thr (spill), reg-persist (spill),
// AGPR-park (+300us: accvgpr_read chains on MFMA critical path). v5 is the
// measured local optimum: fat P1 phase (max load-ILP window, phase-local
// accumulators), QW1h+QW2 in LDS, 512 thr (only shape getting 128 VGPR),
// __syncthreads barriers (compiler scheduling freedom beats vmcnt-drain cost).

typedef unsigned short u16;
typedef unsigned int u32;
typedef __attribute__((ext_vector_type(8))) short short8;
typedef __attribute__((ext_vector_type(4))) float f32x4;

#define LL 64
#define OBS_ 200
#define ACT_ 6
#define STO 30
#define OUTC 350

// packed-weight unit offsets (1 unit = 1KB = 64 lanes x 16B)
#define U_WG   0
#define U_PW1  468
#define U_QW1  559
#define U_PW2  741
#define U_QW2  769
#define U_TOT  797
#define QX_OFF (1u << 20)

__device__ __forceinline__ u16 f2b(float f){
  u32 u = __float_as_uint(f);
  u = (u + 0x7fffu + ((u >> 16) & 1u)) >> 16;   // RNE
  return (u16)u;
}
__device__ __forceinline__ float b2f(u16 h){ return __uint_as_float(((u32)h) << 16); }

// stride-512B tiles (h): swizzle byte ^= (r&7)<<4
__device__ __forceinline__ short8 ldA7(const u16* buf, int r, int colStart){
  return *(const short8*)((const char*)buf + r*512 + ((colStart*2) ^ ((r & 7) << 4)));
}
__device__ __forceinline__ void st27(u16* buf, int r, int c, u16 v){
  *(u16*)((char*)buf + r*512 + ((c*2) ^ ((r & 7) << 4))) = v;
}
__device__ __forceinline__ u16 ld27(const u16* buf, int r, int c){
  return *(const u16*)((const char*)buf + r*512 + ((c*2) ^ ((r & 7) << 4)));
}
// stride-448B tiles (sqq/sob/shh/spp): swizzle byte ^= (r&3)<<4
__device__ __forceinline__ short8 ldA3(const u16* buf, int r, int colStart){
  return *(const short8*)((const char*)buf + r*448 + ((colStart*2) ^ ((r & 3) << 4)));
}
__device__ __forceinline__ void st23(u16* buf, int r, int c, u16 v){
  *(u16*)((char*)buf + r*448 + ((c*2) ^ ((r & 3) << 4))) = v;
}
__device__ __forceinline__ void st8_3(u16* buf, int r, int c8, short8 v){
  *(short8*)((char*)buf + r*448 + ((c8*16) ^ ((r & 3) << 4))) = v;
}
__device__ __forceinline__ short8 ldB(const char* wsb, int unit, int lane){
  return *(const short8*)(wsb + (((size_t)unit) << 10) + ((size_t)lane << 4));
}
__device__ __forceinline__ short8 lwq(const u16* sw, int lu, int lane){
  return *(const short8*)((const char*)sw + ((size_t)lu << 10) + (lane << 4));
}
__device__ __forceinline__ f32x4 mfma(short8 a, short8 b, f32x4 c){
  return __builtin_amdgcn_mfma_f32_16x16x32_bf16(a, b, c, 0, 0, 0);
}
__device__ __forceinline__ float sigm(float x){ return 1.f / (1.f + __expf(-x)); }
__device__ __forceinline__ float tanhf_(float x){
  x = fminf(fmaxf(x, -15.f), 15.f);
  float e = __expf(-2.f * x);
  return (1.f - e) / (1.f + e);
}
__device__ __forceinline__ float softplus_(float x){
  return (x > 20.f) ? x : log1pf(__expf(x));
}
__device__ __forceinline__ short8 pack8(f32x4 a, f32x4 b){
  short8 v;
  v[0]=(short)f2b(a[0]); v[1]=(short)f2b(a[1]); v[2]=(short)f2b(a[2]); v[3]=(short)f2b(a[3]);
  v[4]=(short)f2b(b[0]); v[5]=(short)f2b(b[1]); v[6]=(short)f2b(b[2]); v[7]=(short)f2b(b[3]);
  return v;
}

// ---------------- weight packing (UNCHANGED, verified round 1) ---------------
__global__ __launch_bounds__(512) void pack_w(
    const float* W_ih, const float* W_hh, const float* pW1f, const float* qW1f,
    const float* pW2f, const float* qW2f, u16* wsu)
{
  int u = blockIdx.x;
  int t = threadIdx.x;
  int lane = t >> 3, j = t & 7;
  int nl = lane & 15, kg = lane >> 4;
  float v = 0.f;
  if (u < U_PW1) {                       // WG
    int nt = u / 9, ks = u % 9;
    int k = ks*32 + kg*8 + j;
    int c = nt*16 + nl;
    int grow, part, coff;
    if (c < 208)      { grow = c;            part = 0; coff = c; }
    else if (c < 416) { grow = 200 + (c-208); part = 0; coff = c-208; }
    else if (c < 624) { grow = 400 + (c-416); part = 1; coff = c-416; }
    else              { grow = 400 + (c-624); part = 2; coff = c-624; }
    if (coff < 200) {
      if (k < 36)                  { if (part != 2) v = W_ih[grow*36 + k]; }
      else if (k >= 64 && k < 264) { if (part != 1) v = W_hh[grow*200 + (k-64)]; }
    }
  } else if (u < U_QW1) {                // PW1
    int uu = u - U_PW1; int nt = uu / 7, ks = uu % 7;
    int k = ks*32 + kg*8 + j; int n = nt*16 + nl;
    if (n < 200 && k < 200) v = pW1f[n*200 + k];
  } else if (u < U_PW2) {                // QW1
    int uu = u - U_QW1; int nt = uu / 14, ks = uu % 14;
    int k = ks*32 + kg*8 + j; int n = nt*16 + nl;
    if (n < 200) {
      if (k < 200) v = qW1f[n*400 + k];
      else if (k >= 224 && k < 424) v = qW1f[n*400 + 200 + (k-224)];
    }
  } else {                               // PW2 / QW2
    bool isQ = (u >= U_QW2);
    int uu = u - (isQ ? U_QW2 : U_PW2); int nt = uu / 7, ks = uu % 7;
    int k = ks*32 + kg*8 + j; int c = nt*16 + nl;
    int row = (c < 32) ? c : 30 + (c - 32);
    bool ok = (c < 32) ? (c < 30) : ((c - 32) < 30);
    const float* W = isQ ? qW2f : pW2f;
    if (ok && k < 200) v = W[row*200 + k];
  }
  wsu[((size_t)u << 9) + lane*8 + j] = f2b(v);
}

// ---------------- qx kernel (UNCHANGED, verified round 4) --------------------
__global__ __launch_bounds__(512) void qx_k(
    const float* __restrict__ obs, const float* __restrict__ qb1,
    const char* __restrict__ wsb, u16* __restrict__ qxp)
{
  const int tid = threadIdx.x, w = tid >> 6, lane = tid & 63;
  const int nl = lane & 15, kg = lane >> 4;
  const int r0 = blockIdx.x * 16;
  __shared__ __align__(16) u16 sob[16*224];
  for (int i = tid; i < 16*224; i += 512) sob[i] = 0;
  __syncthreads();
  if (tid < 400) {
    int m = tid / 25, c8 = tid % 25;
    const float* op = obs + (size_t)(r0+m)*OBS_ + c8*8;
    f32x4 a = *(const f32x4*)op, b = *(const f32x4*)(op + 4);
    st8_3(sob, m, c8, pack8(a, b));
  }
  __syncthreads();
#pragma unroll
  for (int qi = 0; qi < 2; ++qi) {
    int tq = w + qi*8;
    if (tq < 13) {
      f32x4 acc{0,0,0,0};
#pragma unroll
      for (int ks = 0; ks < 7; ++ks)
        acc = mfma(ldA3(sob, nl, ks*32 + kg*8), ldB(wsb, U_QW1 + tq*14 + ks, lane), acc);
      int n = tq*16 + nl;
      if (n < 200) {
        float b = qb1[n];
#pragma unroll
        for (int i = 0; i < 4; ++i)
          qxp[(size_t)(r0 + kg*4 + i)*OBS_ + n] = f2b(acc[i] + b);
      }
    }
  }
}

// ---------------- prior kernel (UNCHANGED, verified round 4) -----------------
__global__ __launch_bounds__(512) void prior_k(
    const float* __restrict__ pb1, const float* __restrict__ pb2,
    const char* __restrict__ wsb, float* __restrict__ out)
{
  const int tid = threadIdx.x, w = tid >> 6, lane = tid & 63;
  const int nl = lane & 15, kg = lane >> 4;
  const int r0 = blockIdx.x * 16;
  __shared__ __align__(16) u16 shh[16*224];
  __shared__ __align__(16) u16 spp[16*224];
  for (int i = tid; i < 16*224; i += 512) { shh[i] = 0; spp[i] = 0; }
  __syncthreads();
  if (tid < 400) {
    int m = tid / 25, c8 = tid % 25;
    const float* hp = out + (size_t)(r0+m)*OUTC + 150 + c8*8;
    f32x4 a, b;
#pragma unroll
    for (int i = 0; i < 4; ++i) { a[i] = hp[i]; b[i] = hp[4+i]; }
    st8_3(shh, m, c8, pack8(a, b));
  }
  __syncthreads();
#pragma unroll
  for (int qi = 0; qi < 2; ++qi) {
    int tq = w + qi*8;
    if (tq < 13) {
      f32x4 acc{0,0,0,0};
#pragma unroll
      for (int ks = 0; ks < 7; ++ks)
        acc = mfma(ldA3(shh, nl, ks*32 + kg*8), ldB(wsb, U_PW1 + tq*7 + ks, lane), acc);
      int n = tq*16 + nl;
      if (n < 200) {
        float b = pb1[n];
#pragma unroll
        for (int i = 0; i < 4; ++i) {
          float v = acc[i] + b;
          st23(spp, kg*4 + i, n, f2b(v > 0.f ? v : 0.f));
        }
      }
    }
  }
  __syncthreads();
  if (w < 2) {
    f32x4 a0{0,0,0,0}, a1{0,0,0,0};
#pragma unroll
    for (int ks = 0; ks < 7; ++ks) {
      short8 af = ldA3(spp, nl, ks*32 + kg*8);
      a0 = mfma(af, ldB(wsb, U_PW2 + w*7 + ks,     lane), a0);
      a1 = mfma(af, ldB(wsb, U_PW2 + (w+2)*7 + ks, lane), a1);
    }
    int c3 = w*16 + nl;
    if (c3 < 30) {
      float bmu = pb2[c3], bpre = pb2[30 + c3];
#pragma unroll
      for (int i = 0; i < 4; ++i) {
        size_t ob = (size_t)(r0 + kg*4 + i)*OUTC;
        out[ob + c3] = a0[i] + bmu;
        float sp = softplus_(a1[i] + bpre) + 1e-5f;
        out[ob + 30 + c3] = fmaxf(sp, 1e-4f);
      }
    }
  }
}

// ---------------- sequential scan (v5 verbatim) ------------------------------
__global__ __launch_bounds__(512, 2) void rssm_seq(
    const float* __restrict__ act, const float* __restrict__ noise,
    const float* __restrict__ b_ih, const float* __restrict__ b_hh,
    const float* __restrict__ qb2,
    const u16* __restrict__ qxp, const char* __restrict__ wsb,
    float* __restrict__ out)
{
  const int tid  = threadIdx.x;
  const int w    = tid >> 6;      // wave 0..7
  const int lane = tid & 63;
  const int nl   = lane & 15;
  const int kg   = lane >> 4;
  const int m0   = blockIdx.x * 16;

  // LDS weight cache: 119 units = QW1h (tq*7+ks, 91) then QW2 (nt*7+ks, 28)
  __shared__ __align__(16) u16 swq[119*512];
  // h0/h1: [16][256] stride 512B: h 0..199 | s 200..229 | a 230..235 | zeros
  __shared__ __align__(16) u16 h0 [16*256];
  __shared__ __align__(16) u16 h1 [16*256];
  __shared__ __align__(16) u16 sqq[16*224];   // stride 448B

  for (int i = tid; i < 16*256; i += 512) { h0[i]=0; h1[i]=0; }
  for (int i = tid; i < 16*224; i += 512) sqq[i]=0;
  // load LDS weight cache (one-time, 119KB)
  for (int c = tid; c < 119*64; c += 512) {
    int lu = c >> 6, l16 = c & 63;
    int gu = (lu < 91) ? (U_QW1 + (lu/7)*14 + 7 + (lu%7)) : (U_QW2 + (lu - 91));
    *(short8*)((char*)swq + (size_t)c*16) =
        *(const short8*)(wsb + ((size_t)gu << 10) + (l16 << 4));
  }

  // ---- roles ----
  // P1/P2 job1: tq = w (all 8 waves). job2 (waves 3..7): tq2 = w+5 (8..12).
  const int  cj  = w*16 + nl;                       // < 128, always valid
  const bool j2  = (w >= 3);
  const int  tq2 = w + 5;
  const int  cj2 = tq2*16 + nl;
  const bool cj2v = j2 && (cj2 < 200);
  const float bR1 = b_ih[cj]       + b_hh[cj];
  const float bZ1 = b_ih[200 + cj] + b_hh[200 + cj];
  const float bI1 = b_ih[400 + cj];
  const float bH1 = b_hh[400 + cj];
  float bR2=0,bZ2=0,bI2=0,bH2=0;
  if (cj2v) {
    bR2 = b_ih[cj2] + b_hh[cj2];
    bZ2 = b_ih[200+cj2] + b_hh[200+cj2];
    bI2 = b_ih[400+cj2];
    bH2 = b_hh[400+cj2];
  }
  // P3: waves 0,1 (mu tile w, pre tile w+2 of QW2)
  const bool isP3 = (w < 2);
  const int  c3   = w*16 + nl;
  const bool c3v  = isP3 && (c3 < 30);
  float b3mu=0, b3pre=0;
  if (c3v) { b3mu = qb2[c3]; b3pre = qb2[30 + c3]; }
  // act stagers: waves 2,3 (96 lanes)
  const int  t2 = (w - 2)*64 + lane;
  const bool isAct = (w == 2 || w == 3) && (t2 < 96);

  __syncthreads();
  // prologue: act(l=0) -> h0 cols 230..235 (s0=h0=0 already)
  if (tid < 96) {
    int m = tid / 6, j = tid % 6;
    st27(h0, m, 230 + j, f2b(act[(size_t)(m0+m)*LL*ACT_ + j]));
  }
  __syncthreads();

#pragma unroll 1
  for (int l = 0; l < LL; ++l) {
    u16* hO = (l & 1) ? h1 : h0;
    u16* hN = (l & 1) ? h0 : h1;
    const size_t outB = (size_t)l*OUTC;

    // ---- step-start prefetches (consumed 1-2 phases later) ----
    float ep[4] = {0,0,0,0};
    if (c3v) {
      const float* np = noise + (size_t)(m0 + kg*4)*LL*STO + (size_t)l*STO + c3;
#pragma unroll
      for (int i = 0; i < 4; ++i) ep[i] = np[(size_t)i*LL*STO];
    }
    float qx1[4], qx2[4] = {0,0,0,0};
#pragma unroll
    for (int i = 0; i < 4; ++i)
      qx1[i] = b2f(qxp[((size_t)(m0 + kg*4 + i)*LL + l)*OBS_ + cj]);
    if (cj2v) {
#pragma unroll
      for (int i = 0; i < 4; ++i)
        qx2[i] = b2f(qxp[((size_t)(m0 + kg*4 + i)*LL + l)*OBS_ + cj2]);
    }
    float av = 0.f;
    if (isAct && (l + 1 < LL))
      av = act[((size_t)(m0 + t2/6)*LL + (l+1))*ACT_ + (t2 % 6)];

    // ================= P1: GRU gates (L2 weight stream) =====================
    short8 a9[9];
#pragma unroll
    for (int ks = 0; ks < 9; ++ks) {
      const int col = (ks < 2) ? (200 + ks*32 + kg*8) : ((ks-2)*32 + kg*8);
      a9[ks] = ldA7(hO, nl, col);
    }
    if (!j2) {
      f32x4 aR{0,0,0,0}, aZ{0,0,0,0}, aI{0,0,0,0}, aH{0,0,0,0};
#pragma unroll
      for (int ks = 0; ks < 9; ++ks) {
        aR = mfma(a9[ks], ldB(wsb, U_WG + w*9 + ks,      lane), aR);
        aZ = mfma(a9[ks], ldB(wsb, U_WG + (13+w)*9 + ks, lane), aZ);
        if (ks < 2) aI = mfma(a9[ks], ldB(wsb, U_WG + (26+w)*9 + ks, lane), aI);
        else        aH = mfma(a9[ks], ldB(wsb, U_WG + (39+w)*9 + ks, lane), aH);
      }
#pragma unroll
      for (int i = 0; i < 4; ++i) {
        int m = kg*4 + i;
        float r = sigm(aR[i] + bR1);
        float z = sigm(aZ[i] + bZ1);
        float n = tanhf_(aI[i] + bI1 + r*(aH[i] + bH1));
        float hold = b2f(ld27(hO, m, cj));
        float hnew = (1.f - z)*n + z*hold;
        st27(hN, m, cj, f2b(hnew));
        out[(size_t)(m0+m)*LL*OUTC + outB + 150 + cj] = hnew;
      }
    } else {
      f32x4 aR1{0,0,0,0}, aZ1{0,0,0,0}, aI1{0,0,0,0}, aH1{0,0,0,0};
      f32x4 aR2{0,0,0,0}, aZ2{0,0,0,0}, aI2{0,0,0,0}, aH2{0,0,0,0};
#pragma unroll
      for (int ks = 0; ks < 9; ++ks) {
        aR1 = mfma(a9[ks], ldB(wsb, U_WG + w*9 + ks,        lane), aR1);
        aR2 = mfma(a9[ks], ldB(wsb, U_WG + tq2*9 + ks,      lane), aR2);
        aZ1 = mfma(a9[ks], ldB(wsb, U_WG + (13+w)*9 + ks,   lane), aZ1);
        aZ2 = mfma(a9[ks], ldB(wsb, U_WG + (13+tq2)*9 + ks, lane), aZ2);
        if (ks < 2) {
          aI1 = mfma(a9[ks], ldB(wsb, U_WG + (26+w)*9 + ks,   lane), aI1);
          aI2 = mfma(a9[ks], ldB(wsb, U_WG + (26+tq2)*9 + ks, lane), aI2);
        } else {
          aH1 = mfma(a9[ks], ldB(wsb, U_WG + (39+w)*9 + ks,   lane), aH1);
          aH2 = mfma(a9[ks], ldB(wsb, U_WG + (39+tq2)*9 + ks, lane), aH2);
        }
      }
#pragma unroll
      for (int i = 0; i < 4; ++i) {
        int m = kg*4 + i;
        float r = sigm(aR1[i] + bR1);
        float z = sigm(aZ1[i] + bZ1);
        float n = tanhf_(aI1[i] + bI1 + r*(aH1[i] + bH1));
        float hold = b2f(ld27(hO, m, cj));
        float hnew = (1.f - z)*n + z*hold;
        st27(hN, m, cj, f2b(hnew));
        out[(size_t)(m0+m)*LL*OUTC + outB + 150 + cj] = hnew;
      }
      if (cj2 < 200) {
#pragma unroll
        for (int i = 0; i < 4; ++i) {
          int m = kg*4 + i;
          float r = sigm(aR2[i] + bR2);
          float z = sigm(aZ2[i] + bZ2);
          float n = tanhf_(aI2[i] + bI2 + r*(aH2[i] + bH2));
          float hold = b2f(ld27(hO, m, cj2));
          float hnew = (1.f - z)*n + z*hold;
          st27(hN, m, cj2, f2b(hnew));
          out[(size_t)(m0+m)*LL*OUTC + outB + 150 + cj2] = hnew;
        }
      }
    }
    __syncthreads();

    // ================= P2: q1h GEMM (LDS weights) ===========================
    {
      short8 g[7];
#pragma unroll
      for (int ks = 0; ks < 7; ++ks) g[ks] = ldA7(hN, nl, ks*32 + kg*8);
      f32x4 aq1{0,0,0,0}, aq2{0,0,0,0};
#pragma unroll
      for (int ks = 0; ks < 7; ++ks) {
        aq1 = mfma(g[ks], lwq(swq, w*7 + ks, lane), aq1);
        if (j2) aq2 = mfma(g[ks], lwq(swq, tq2*7 + ks, lane), aq2);
      }
#pragma unroll
      for (int i = 0; i < 4; ++i) {
        int m = kg*4 + i;
        float v = aq1[i] + qx1[i];
        st23(sqq, m, cj, f2b(v > 0.f ? v : 0.f));
      }
      if (cj2v) {
#pragma unroll
        for (int i = 0; i < 4; ++i) {
          int m = kg*4 + i;
          float v = aq2[i] + qx2[i];
          st23(sqq, m, cj2, f2b(v > 0.f ? v : 0.f));
        }
      }
    }
    __syncthreads();

    // ================= P3: q2 heads + reparam (waves 0,1; LDS weights) ======
    if (isP3) {
      f32x4 a0{0,0,0,0}, a1{0,0,0,0};
#pragma unroll
      for (int ks = 0; ks < 7; ++ks) {
        short8 af = ldA3(sqq, nl, ks*32 + kg*8);
        a0 = mfma(af, lwq(swq, 91 + w*7 + ks,     lane), a0);
        a1 = mfma(af, lwq(swq, 91 + (w+2)*7 + ks, lane), a1);
      }
      if (c3 < 30) {
#pragma unroll
        for (int i = 0; i < 4; ++i) {
          int m = kg*4 + i;
          size_t ob = (size_t)(m0+m)*LL*OUTC + outB;
          float mu = a0[i] + b3mu;
          float sp = softplus_(a1[i] + b3pre) + 1e-5f;
          float sd = fmaxf(sp, 1e-4f);
          float s = mu + sd*ep[i];
          out[ob +  60 + c3] = mu;
          out[ob +  90 + c3] = sd;
          out[ob + 120 + c3] = s;
          st27(hN, m, 200 + c3, f2b(s));
        }
      }
    } else if (isAct && (l + 1 < LL)) {
      st27(hN, t2/6, 230 + (t2 % 6), f2b(av));
    }
    __syncthreads();
  }
}

extern "C" void kernel_launch(void* const* d_in, const int* in_sizes, int n_in,
                              void* d_out, int out_size, void* d_ws, size_t ws_size,
                              hipStream_t stream) {
  const float* obs   = (const float*)d_in[0];
  const float* act   = (const float*)d_in[1];
  const float* noise = (const float*)d_in[2];
  const float* W_ih  = (const float*)d_in[3];
  const float* b_ih  = (const float*)d_in[4];
  const float* W_hh  = (const float*)d_in[5];
  const float* b_hh  = (const float*)d_in[6];
  const float* pW1   = (const float*)d_in[7];
  const float* pb1   = (const float*)d_in[8];
  const float* pW2   = (const float*)d_in[9];
  const float* pb2   = (const float*)d_in[10];
  const float* qW1   = (const float*)d_in[11];
  const float* qb1   = (const float*)d_in[12];
  const float* qW2   = (const float*)d_in[13];
  const float* qb2   = (const float*)d_in[14];
  float* out = (float*)d_out;
  u16* qxp = (u16*)((char*)d_ws + QX_OFF);

  pack_w<<<U_TOT, 512, 0, stream>>>(W_ih, W_hh, pW1, qW1, pW2, qW2, (u16*)d_ws);
  qx_k<<<8192, 512, 0, stream>>>(obs, qb1, (const char*)d_ws, qxp);
  rssm_seq<<<128, 512, 0, stream>>>(act, noise, b_ih, b_hh, qb2,
                                    qxp, (const char*)d_ws, out);
  prior_k<<<8192, 512, 0, stream>>>(pb1, pb2, (const char*)d_ws, out);
}